// Round 6
// baseline (523.402 us; speedup 1.0000x reference)
//
#include <hip/hip_runtime.h>
#include <hip/hip_bf16.h>
#include <math.h>
#include <float.h>

// VQVAE forward, MI355X. Round 6: LDS-free, barrier-free register GEMMs.
// All operands in pre-shuffled MFMA-native layout [tile16xK32][lane][16B] so a
// wave's fragment = one coalesced global_load_dwordx4; compiler pipelines with
// fine-grained vmcnt (no barrier => no vmcnt(0) drain). bf16x3 hi/mid split =
// fp32-grade precision at MFMA rate. dist: branchless packed-key top-3 per
// 256-col group (8 groups) + exact fp32 rescore of 24 candidates.

typedef __attribute__((ext_vector_type(8))) short short8;
typedef __attribute__((ext_vector_type(4))) float floatx4;

union Frag { short8 s; unsigned u[4]; unsigned short us[8]; };

__device__ __forceinline__ float bf2f(unsigned short s) {
  union { unsigned u; float f; } v; v.u = ((unsigned)s) << 16; return v.f;
}
__device__ __forceinline__ unsigned pk2(float a, float b) {
  __hip_bfloat162 h = __float22bfloat162_rn(float2{a, b});
  union { __hip_bfloat162 h2; unsigned u; } c; c.h2 = h; return c.u;
}
// RNE hi/mid split of 2 floats, packed (v_cvt_pk_bf16_f32 path)
__device__ __forceinline__ void split2(float a, float b, unsigned& hi, unsigned& mid) {
  hi = pk2(a, b);
  mid = pk2(a - bf2f((unsigned short)(hi & 0xFFFFu)),
            b - bf2f((unsigned short)(hi >> 16)));
}

__device__ __forceinline__ unsigned packkey(float d, int c) {
  unsigned b = __float_as_uint(d);
  b = (b & 0x80000000u) ? ~b : (b | 0x80000000u);
  return (b & 0xFFFFF800u) | (unsigned)c;
}
__device__ __forceinline__ void ins3(unsigned k, unsigned& v1, unsigned& v2,
                                     unsigned& v3) {
  unsigned t1 = min(v1, k), c1 = max(v1, k);
  unsigned t2 = min(v2, c1), c2 = max(v2, c1);
  v1 = t1; v2 = t2; v3 = min(v3, c2);
}

// W[Nw][Kw] fp32 -> B-shuffled hi/mid, zero-padded to (16*ntiles, 32*KT).
// one wave per (ntile, kt); gwid == ntile*KT + kt.
__global__ __launch_bounds__(256) void shuf_w(
    const float* __restrict__ W, unsigned short* __restrict__ oh,
    unsigned short* __restrict__ om, int Nw, int Kw, int KT) {
  const int wave = threadIdx.x >> 6, lane = threadIdx.x & 63;
  const int gwid = blockIdx.x * 4 + wave;
  const int ntile = gwid / KT, kt = gwid % KT;
  const int row = ntile * 16 + (lane & 15);
  const int k0 = kt * 32 + (lane >> 4) * 8;
  float v[8];
#pragma unroll
  for (int j = 0; j < 8; j++) {
    const int kc = k0 + j;
    v[j] = (row < Nw && kc < Kw) ? W[(long)row * Kw + kc] : 0.f;
  }
  Frag h, m;
#pragma unroll
  for (int j = 0; j < 4; j++) split2(v[2 * j], v[2 * j + 1], h.u[j], m.u[j]);
  const long off = ((long)gwid * 64 + lane) * 8;
  *(short8*)(oh + off) = h.s;
  *(short8*)(om + off) = m.s;
}

// fp32 -> row-major bf16 hi/mid (2 elems/thread)
__global__ __launch_bounds__(256) void conv_row(
    const float* __restrict__ src, unsigned short* __restrict__ oh,
    unsigned short* __restrict__ om, int n2) {
  const long t = (long)blockIdx.x * 256 + threadIdx.x;
  if (t >= n2) return;
  unsigned hi, mid;
  split2(src[2 * t], src[2 * t + 1], hi, mid);
  *(unsigned*)(oh + 2 * t) = hi;
  *(unsigned*)(om + 2 * t) = mid;
}

__global__ __launch_bounds__(256) void emb_norm(const float* __restrict__ emb,
                                                float* __restrict__ enorm) {
  const int gtid = blockIdx.x * 256 + threadIdx.x;
  const int j = gtid >> 6;
  const int lane = threadIdx.x & 63;
  float4 v = *(const float4*)(emb + (long)j * 256 + (lane << 2));
  float s = v.x * v.x + v.y * v.y + v.z * v.z + v.w * v.w;
#pragma unroll
  for (int off = 1; off < 64; off <<= 1) s += __shfl_xor(s, off, 64);
  if (lane == 0) enorm[j] = s;
}

enum { EPI_NONE = 0, EPI_RELU = 1, EPI_SIGMOID = 2 };
// AMODE: 0 = shuffled bf16 A, 1 = fp32 row-major A (in-loop split), 2 = row-major bf16 gather via aidx
// OMODE: 0 = fp32 out, 1 = shuffled hi/mid out (next GEMM's A operand)

template <int TM, int EPI, int AMODE, int OMODE>
__global__ __launch_bounds__(256, 2) void rgemm(
    const float* __restrict__ Af,
    const unsigned short* __restrict__ AsH, const unsigned short* __restrict__ AsM,
    const unsigned short* __restrict__ Bh, const unsigned short* __restrict__ Bm,
    const float* __restrict__ bias, const int* __restrict__ aidx,
    float* __restrict__ Cf, unsigned short* __restrict__ Oh,
    unsigned short* __restrict__ Om, int M, int N, int K, int Nreal) {
  const int lane = threadIdx.x & 63, wave = threadIdx.x >> 6;
  const int gwid = blockIdx.x * 4 + wave;
  const int ntiles = N >> 6;
  const int band = gwid / ntiles, nt = gwid % ntiles;
  const int row0 = band * (TM * 16), col0 = nt * 64;
  const int KT = K >> 5;
  const int qd = lane >> 4, ln = lane & 15;

  const unsigned short *aH[TM], *aM[TM];
  const float* aF[TM];
#pragma unroll
  for (int tm = 0; tm < TM; tm++) {
    if (AMODE == 0) {
      const long t0 = (long)(row0 / 16 + tm) * KT;
      aH[tm] = AsH + (t0 * 64 + lane) * 8;
      aM[tm] = AsM + (t0 * 64 + lane) * 8;
    } else if (AMODE == 1) {
      aF[tm] = Af + (long)(row0 + tm * 16 + ln) * K + qd * 8;
    } else {
      const long er = aidx[row0 + tm * 16 + ln];
      aH[tm] = AsH + er * K + qd * 8;
      aM[tm] = AsM + er * K + qd * 8;
    }
  }
  const unsigned short *bHp[4], *bMp[4];
#pragma unroll
  for (int tn = 0; tn < 4; tn++) {
    const long t0 = (long)(col0 / 16 + tn) * KT;
    bHp[tn] = Bh + (t0 * 64 + lane) * 8;
    bMp[tn] = Bm + (t0 * 64 + lane) * 8;
  }

  floatx4 acc[TM][4];
#pragma unroll
  for (int i = 0; i < TM; i++)
#pragma unroll
    for (int j = 0; j < 4; j++) acc[i][j] = (floatx4)0.f;

  auto loadB = [&](int kt, Frag (&bh)[4], Frag (&bm)[4]) {
#pragma unroll
    for (int tn = 0; tn < 4; tn++) {
      bh[tn].s = *(const short8*)(bHp[tn] + (long)kt * 512);
      bm[tn].s = *(const short8*)(bMp[tn] + (long)kt * 512);
    }
  };
  auto loadAS = [&](int kt, Frag (&ah)[TM], Frag (&am)[TM]) {
    const long st = (AMODE == 0) ? (long)kt * 512 : (long)kt * 32;
#pragma unroll
    for (int tm = 0; tm < TM; tm++) {
      ah[tm].s = *(const short8*)(aH[tm] + st);
      am[tm].s = *(const short8*)(aM[tm] + st);
    }
  };
  auto loadAF = [&](int kt, float4 (&f)[TM][2]) {
#pragma unroll
    for (int tm = 0; tm < TM; tm++) {
      f[tm][0] = *(const float4*)(aF[tm] + (long)kt * 32);
      f[tm][1] = *(const float4*)(aF[tm] + (long)kt * 32 + 4);
    }
  };
  auto cvtA = [&](float4 (&f)[TM][2], Frag (&ah)[TM], Frag (&am)[TM]) {
#pragma unroll
    for (int tm = 0; tm < TM; tm++) {
      split2(f[tm][0].x, f[tm][0].y, ah[tm].u[0], am[tm].u[0]);
      split2(f[tm][0].z, f[tm][0].w, ah[tm].u[1], am[tm].u[1]);
      split2(f[tm][1].x, f[tm][1].y, ah[tm].u[2], am[tm].u[2]);
      split2(f[tm][1].z, f[tm][1].w, ah[tm].u[3], am[tm].u[3]);
    }
  };
  auto domfma = [&](Frag (&xh)[TM], Frag (&xm)[TM], Frag (&yh)[4], Frag (&ym)[4]) {
#pragma unroll
    for (int tn = 0; tn < 4; tn++)
#pragma unroll
      for (int tm = 0; tm < TM; tm++) {
        acc[tm][tn] = __builtin_amdgcn_mfma_f32_16x16x32_bf16(xh[tm].s, yh[tn].s, acc[tm][tn], 0, 0, 0);
        acc[tm][tn] = __builtin_amdgcn_mfma_f32_16x16x32_bf16(xh[tm].s, ym[tn].s, acc[tm][tn], 0, 0, 0);
        acc[tm][tn] = __builtin_amdgcn_mfma_f32_16x16x32_bf16(xm[tm].s, yh[tn].s, acc[tm][tn], 0, 0, 0);
      }
  };

  Frag ah[TM], am[TM], bh[4], bm[4];
  Frag nah[TM], nam[TM], nbh[4], nbm[4];
  float4 fa[TM][2], nfa[TM][2];

  if (AMODE == 1) loadAF(0, fa); else loadAS(0, ah, am);
  loadB(0, bh, bm);
#pragma unroll 2
  for (int kt = 0; kt < KT - 1; kt++) {
    if (AMODE == 1) loadAF(kt + 1, nfa); else loadAS(kt + 1, nah, nam);
    loadB(kt + 1, nbh, nbm);
    if (AMODE == 1) cvtA(fa, ah, am);
    domfma(ah, am, bh, bm);
#pragma unroll
    for (int tm = 0; tm < TM; tm++) {
      if (AMODE == 1) { fa[tm][0] = nfa[tm][0]; fa[tm][1] = nfa[tm][1]; }
      else { ah[tm] = nah[tm]; am[tm] = nam[tm]; }
    }
#pragma unroll
    for (int tn = 0; tn < 4; tn++) { bh[tn] = nbh[tn]; bm[tn] = nbm[tn]; }
  }
  if (AMODE == 1) cvtA(fa, ah, am);
  domfma(ah, am, bh, bm);

  // C/D layout: col = lane&15, row = qd*4 + reg (within 16-row tile)
  const int KTo = N >> 5;
#pragma unroll
  for (int tn = 0; tn < 4; tn++) {
    const int c = col0 + tn * 16 + ln;
    const float bb = (c < Nreal) ? bias[c] : 0.f;
#pragma unroll
    for (int tm = 0; tm < TM; tm++) {
      float v[4];
#pragma unroll
      for (int reg = 0; reg < 4; reg++) {
        float t = acc[tm][tn][reg] + bb;
        if (EPI == EPI_RELU) t = fmaxf(t, 0.f);
        if (EPI == EPI_SIGMOID) t = 1.f / (1.f + __expf(-t));
        v[reg] = t;
      }
      if (OMODE == 0) {
#pragma unroll
        for (int reg = 0; reg < 4; reg++)
          Cf[(long)(row0 + tm * 16 + qd * 4 + reg) * N + c] = v[reg];
      } else {
        unsigned h01, m01, h23, m23;
        split2(v[0], v[1], h01, m01);
        split2(v[2], v[3], h23, m23);
        const long tile = (long)(row0 / 16 + tm) * KTo + (c >> 5);
        const int lp0 = qd * 4 + ((c >> 3) & 3) * 16;
        const long base = tile * 512 + (c & 7);
        Oh[base + (long)(lp0 + 0) * 8] = (unsigned short)(h01 & 0xFFFFu);
        Oh[base + (long)(lp0 + 1) * 8] = (unsigned short)(h01 >> 16);
        Oh[base + (long)(lp0 + 2) * 8] = (unsigned short)(h23 & 0xFFFFu);
        Oh[base + (long)(lp0 + 3) * 8] = (unsigned short)(h23 >> 16);
        Om[base + (long)(lp0 + 0) * 8] = (unsigned short)(m01 & 0xFFFFu);
        Om[base + (long)(lp0 + 1) * 8] = (unsigned short)(m01 >> 16);
        Om[base + (long)(lp0 + 2) * 8] = (unsigned short)(m23 & 0xFFFFu);
        Om[base + (long)(lp0 + 3) * 8] = (unsigned short)(m23 >> 16);
      }
    }
  }
}

// dist candidates: wave = (row-band 64, col-group g of 256 cols = 4 n-tiles).
// Register K-loop (K=256, KT=8), per-lane packed-key top-3, one 16-lane merge.
__global__ __launch_bounds__(256, 2) void dist_topk(
    const unsigned short* __restrict__ ZsH, const unsigned short* __restrict__ ZsM,
    const unsigned short* __restrict__ EbH, const unsigned short* __restrict__ EbM,
    const float* __restrict__ enorm, int* __restrict__ pidx, int M) {
  const int lane = threadIdx.x & 63, wave = threadIdx.x >> 6;
  const int gwid = blockIdx.x * 4 + wave;
  const int band = gwid >> 3, g = gwid & 7;
  const int row0 = band * 64;
  const int qd = lane >> 4, ln = lane & 15;

  const unsigned short *aH[4], *aM[4];
#pragma unroll
  for (int tm = 0; tm < 4; tm++) {
    const long t0 = (long)(row0 / 16 + tm) * 8;
    aH[tm] = ZsH + (t0 * 64 + lane) * 8;
    aM[tm] = ZsM + (t0 * 64 + lane) * 8;
  }

  unsigned k1[16], k2[16], k3[16];
#pragma unroll
  for (int s = 0; s < 16; s++) { k1[s] = 0xFFFFFFFFu; k2[s] = 0xFFFFFFFFu; k3[s] = 0xFFFFFFFFu; }

  for (int nn = 0; nn < 4; nn++) {
    const int nt64 = g * 4 + nn;
    const int col0 = nt64 * 64;
    const unsigned short *bHp[4], *bMp[4];
#pragma unroll
    for (int tn = 0; tn < 4; tn++) {
      const long t0 = (long)(nt64 * 4 + tn) * 8;
      bHp[tn] = EbH + (t0 * 64 + lane) * 8;
      bMp[tn] = EbM + (t0 * 64 + lane) * 8;
    }
    floatx4 acc[4][4];
#pragma unroll
    for (int i = 0; i < 4; i++)
#pragma unroll
      for (int j = 0; j < 4; j++) acc[i][j] = (floatx4)0.f;

    Frag ah[4], am[4], bh[4], bm[4], nah[4], nam[4], nbh[4], nbm[4];
#pragma unroll
    for (int t = 0; t < 4; t++) {
      ah[t].s = *(const short8*)(aH[t]); am[t].s = *(const short8*)(aM[t]);
      bh[t].s = *(const short8*)(bHp[t]); bm[t].s = *(const short8*)(bMp[t]);
    }
#pragma unroll 2
    for (int kt = 0; kt < 7; kt++) {
      const long st = (long)(kt + 1) * 512;
#pragma unroll
      for (int t = 0; t < 4; t++) {
        nah[t].s = *(const short8*)(aH[t] + st); nam[t].s = *(const short8*)(aM[t] + st);
        nbh[t].s = *(const short8*)(bHp[t] + st); nbm[t].s = *(const short8*)(bMp[t] + st);
      }
#pragma unroll
      for (int tn = 0; tn < 4; tn++)
#pragma unroll
        for (int tm = 0; tm < 4; tm++) {
          acc[tm][tn] = __builtin_amdgcn_mfma_f32_16x16x32_bf16(ah[tm].s, bh[tn].s, acc[tm][tn], 0, 0, 0);
          acc[tm][tn] = __builtin_amdgcn_mfma_f32_16x16x32_bf16(ah[tm].s, bm[tn].s, acc[tm][tn], 0, 0, 0);
          acc[tm][tn] = __builtin_amdgcn_mfma_f32_16x16x32_bf16(am[tm].s, bh[tn].s, acc[tm][tn], 0, 0, 0);
        }
#pragma unroll
      for (int t = 0; t < 4; t++) {
        ah[t] = nah[t]; am[t] = nam[t]; bh[t] = nbh[t]; bm[t] = nbm[t];
      }
    }
#pragma unroll
    for (int tn = 0; tn < 4; tn++)
#pragma unroll
      for (int tm = 0; tm < 4; tm++) {
        acc[tm][tn] = __builtin_amdgcn_mfma_f32_16x16x32_bf16(ah[tm].s, bh[tn].s, acc[tm][tn], 0, 0, 0);
        acc[tm][tn] = __builtin_amdgcn_mfma_f32_16x16x32_bf16(ah[tm].s, bm[tn].s, acc[tm][tn], 0, 0, 0);
        acc[tm][tn] = __builtin_amdgcn_mfma_f32_16x16x32_bf16(am[tm].s, bh[tn].s, acc[tm][tn], 0, 0, 0);
      }

#pragma unroll
    for (int tn = 0; tn < 4; tn++) {
      const int c = col0 + tn * 16 + ln;
      const float en = enorm[c];
#pragma unroll
      for (int tm = 0; tm < 4; tm++)
#pragma unroll
        for (int reg = 0; reg < 4; reg++) {
          const float d = en - 2.f * acc[tm][tn][reg];
          ins3(packkey(d, c), k1[tm * 4 + reg], k2[tm * 4 + reg], k3[tm * 4 + reg]);
        }
    }
  }

#pragma unroll
  for (int s = 0; s < 16; s++) {
#pragma unroll
    for (int off = 1; off < 16; off <<= 1) {
      unsigned o1 = __shfl_xor(k1[s], off, 64);
      unsigned o2 = __shfl_xor(k2[s], off, 64);
      unsigned o3 = __shfl_xor(k3[s], off, 64);
      ins3(o1, k1[s], k2[s], k3[s]);
      ins3(o2, k1[s], k2[s], k3[s]);
      ins3(o3, k1[s], k2[s], k3[s]);
    }
  }
  if (ln == 0) {
#pragma unroll
    for (int s = 0; s < 16; s++) {
      const int row = row0 + (s >> 2) * 16 + qd * 4 + (s & 3);
      const long base = ((long)g * M + row) * 4;
      pidx[base + 0] = (int)(k1[s] & 0x7FFu);
      pidx[base + 1] = (int)(k2[s] & 0x7FFu);
      pidx[base + 2] = (int)(k3[s] & 0x7FFu);
    }
  }
}

// exact fp32 rescore of 24 candidates/row; z reconstructed from shuffled hi/mid
__global__ __launch_bounds__(256) void rescore(
    const unsigned short* __restrict__ ZsH, const unsigned short* __restrict__ ZsM,
    const float* __restrict__ emb, const float* __restrict__ enorm,
    const int* __restrict__ pidx, int* __restrict__ idx, int M) {
  const int wave = threadIdx.x >> 6, lane = threadIdx.x & 63;
  const int r = blockIdx.x * 4 + wave;
  const int k0 = lane * 4;
  const long tile = (long)(r >> 4) * 8 + (k0 >> 5);
  const int lp = (r & 15) + ((k0 >> 3) & 3) * 16;
  const long off = tile * 512 + (long)lp * 8 + (k0 & 7);
  float4 zv;
  zv.x = bf2f(ZsH[off + 0]) + bf2f(ZsM[off + 0]);
  zv.y = bf2f(ZsH[off + 1]) + bf2f(ZsM[off + 1]);
  zv.z = bf2f(ZsH[off + 2]) + bf2f(ZsM[off + 2]);
  zv.w = bf2f(ZsH[off + 3]) + bf2f(ZsM[off + 3]);
  float best = FLT_MAX;
  int bi = 0x7fffffff;
  for (int g = 0; g < 8; g++) {
#pragma unroll
    for (int s = 0; s < 3; s++) {
      const int j = pidx[((long)g * M + r) * 4 + s];
      float4 ev = *(const float4*)(emb + (long)j * 256 + k0);
      float t = zv.x * ev.x + zv.y * ev.y + zv.z * ev.z + zv.w * ev.w;
#pragma unroll
      for (int off2 = 1; off2 < 64; off2 <<= 1) t += __shfl_xor(t, off2, 64);
      const float d = enorm[j] - 2.f * t;
      if (d < best || (d == best && j < bi)) { best = d; bi = j; }
    }
  }
  if (lane == 0) idx[r] = bi;
}

extern "C" void kernel_launch(void* const* d_in, const int* in_sizes, int n_in,
                              void* d_out, int out_size, void* d_ws, size_t ws_size,
                              hipStream_t stream) {
  const float* x   = (const float*)d_in[0];
  const float* W1  = (const float*)d_in[1];
  const float* b1  = (const float*)d_in[2];
  const float* W2  = (const float*)d_in[3];
  const float* b2  = (const float*)d_in[4];
  const float* W3  = (const float*)d_in[5];
  const float* b3  = (const float*)d_in[6];
  const float* W4  = (const float*)d_in[7];
  const float* b4  = (const float*)d_in[8];
  const float* emb = (const float*)d_in[9];
  float* out = (float*)d_out;

  const int BZ = 16384, IN = 1024, H = 400, Hp = 512, D = 256, NE = 2048;

  char* ws = (char*)d_ws;
  size_t off = 0;
  auto alloc = [&](size_t bytes) {
    void* p = ws + off;
    off += (bytes + 255) & ~(size_t)255;
    return p;
  };
  unsigned short* w1h = (unsigned short*)alloc((size_t)Hp * IN * 2);
  unsigned short* w1m = (unsigned short*)alloc((size_t)Hp * IN * 2);
  unsigned short* w2h = (unsigned short*)alloc((size_t)D * Hp * 2);
  unsigned short* w2m = (unsigned short*)alloc((size_t)D * Hp * 2);
  unsigned short* w3h = (unsigned short*)alloc((size_t)Hp * D * 2);
  unsigned short* w3m = (unsigned short*)alloc((size_t)Hp * D * 2);
  unsigned short* w4h = (unsigned short*)alloc((size_t)IN * Hp * 2);
  unsigned short* w4m = (unsigned short*)alloc((size_t)IN * Hp * 2);
  unsigned short* ebh = (unsigned short*)alloc((size_t)NE * D * 2);  // B-shuffled
  unsigned short* ebm = (unsigned short*)alloc((size_t)NE * D * 2);
  unsigned short* erh = (unsigned short*)alloc((size_t)NE * D * 2);  // row-major
  unsigned short* erm = (unsigned short*)alloc((size_t)NE * D * 2);
  float* enorm = (float*)alloc((size_t)NE * 4);
  unsigned short* h1h = (unsigned short*)alloc((size_t)BZ * Hp * 2);  // A-shuffled
  unsigned short* h1m = (unsigned short*)alloc((size_t)BZ * Hp * 2);
  unsigned short* zsh = (unsigned short*)alloc((size_t)BZ * D * 2);
  unsigned short* zsm = (unsigned short*)alloc((size_t)BZ * D * 2);
  unsigned short* h3h = (unsigned short*)alloc((size_t)BZ * Hp * 2);
  unsigned short* h3m = (unsigned short*)alloc((size_t)BZ * Hp * 2);
  int* pidx = (int*)alloc((size_t)8 * BZ * 4 * 4);
  int* idx  = (int*)alloc((size_t)BZ * 4);

  // operand conversion (shuffled layouts) + norms
  shuf_w<<<dim3((Hp / 16) * (IN / 32) / 4), dim3(256), 0, stream>>>(W1, w1h, w1m, H, IN, IN / 32);
  shuf_w<<<dim3((D / 16) * (Hp / 32) / 4), dim3(256), 0, stream>>>(W2, w2h, w2m, D, H, Hp / 32);
  shuf_w<<<dim3((Hp / 16) * (D / 32) / 4), dim3(256), 0, stream>>>(W3, w3h, w3m, H, D, D / 32);
  shuf_w<<<dim3((IN / 16) * (Hp / 32) / 4), dim3(256), 0, stream>>>(W4, w4h, w4m, IN, H, Hp / 32);
  shuf_w<<<dim3((NE / 16) * (D / 32) / 4), dim3(256), 0, stream>>>(emb, ebh, ebm, NE, D, D / 32);
  conv_row<<<dim3(NE * D / 2 / 256), dim3(256), 0, stream>>>(emb, erh, erm, NE * D / 2);
  emb_norm<<<dim3(NE * 64 / 256), dim3(256), 0, stream>>>(emb, enorm);

  // h1 = relu(x @ W1^T + b1) -> shuffled hi/mid [BZ x 512]
  rgemm<4, EPI_RELU, 1, 1><<<dim3((BZ / 64) * (Hp / 64) / 4), dim3(256), 0, stream>>>(
      x, nullptr, nullptr, w1h, w1m, b1, nullptr, nullptr, h1h, h1m, BZ, Hp, IN, H);
  // z = h1 @ W2^T + b2 -> shuffled hi/mid [BZ x 256]   (TM=2: 2048 waves)
  rgemm<2, EPI_NONE, 0, 1><<<dim3((BZ / 32) * (D / 64) / 4), dim3(256), 0, stream>>>(
      nullptr, h1h, h1m, w2h, w2m, b2, nullptr, nullptr, zsh, zsm, BZ, D, Hp, D);
  // dist candidates: top-3 per 256-col group (8 groups)
  dist_topk<<<dim3((BZ / 64) * 8 / 4), dim3(256), 0, stream>>>(zsh, zsm, ebh, ebm, enorm, pidx, BZ);
  // exact fp32 rescore -> idx
  rescore<<<dim3(BZ / 4), dim3(256), 0, stream>>>(zsh, zsm, emb, enorm, pidx, idx, BZ);
  // h3 = relu(emb[idx] @ W3^T + b3) -> shuffled hi/mid [BZ x 512]
  rgemm<4, EPI_RELU, 2, 1><<<dim3((BZ / 64) * (Hp / 64) / 4), dim3(256), 0, stream>>>(
      nullptr, erh, erm, w3h, w3m, b3, idx, nullptr, h3h, h3m, BZ, Hp, D, H);
  // out = sigmoid(h3 @ W4^T + b4) -> fp32 [BZ x 1024]
  rgemm<4, EPI_SIGMOID, 0, 0><<<dim3((BZ / 64) * (IN / 64) / 4), dim3(256), 0, stream>>>(
      nullptr, h3h, h3m, w4h, w4m, b4, nullptr, out, nullptr, nullptr, BZ, IN, Hp, IN);
}

// Round 7
// 514.747 us; speedup vs baseline: 1.0168x; 1.0168x over previous
//
#include <hip/hip_runtime.h>
#include <math.h>
#include <float.h>

// VQVAE forward, MI355X. Round 7: R4's proven single-buffered glds+LDS K-loop,
// re-gridded for occupancy: BN=64 tiles -> 1024-2048 blocks (4+ blocks/CU
// co-resident; m114 wave-overlap hides the barrier drain). GEMM2 64x64.
// dist: 8 col-groups of 256 -> 1024 blocks, top-3/group + exact rescore of 24.
// bf16x3 (hi/mid RNE split) MFMA everywhere = fp32-grade accuracy.

typedef __attribute__((ext_vector_type(8))) short short8;      // MFMA A/B frag
typedef __attribute__((ext_vector_type(4))) float floatx4;     // MFMA C/D frag
typedef __attribute__((ext_vector_type(4))) unsigned short ushort4v;

__device__ __forceinline__ unsigned short f2bf(float f) {
  union { float f; unsigned u; } v; v.f = f;
  unsigned u = v.u;
  return (unsigned short)((u + 0x7FFFu + ((u >> 16) & 1u)) >> 16);
}
__device__ __forceinline__ float bf2f(unsigned short s) {
  union { unsigned u; float f; } v; v.u = ((unsigned)s) << 16;
  return v.f;
}

__device__ __forceinline__ void glds16(const void* g, void* l) {
  __builtin_amdgcn_global_load_lds(
      (const __attribute__((address_space(1))) unsigned int*)g,
      (__attribute__((address_space(3))) unsigned int*)l, 16, 0, 0);
}

__device__ __forceinline__ unsigned packkey(float d, int c) {
  unsigned b = __float_as_uint(d);
  b = (b & 0x80000000u) ? ~b : (b | 0x80000000u);
  return (b & 0xFFFFF800u) | (unsigned)c;
}
__device__ __forceinline__ void ins3(unsigned k, unsigned& v1, unsigned& v2,
                                     unsigned& v3) {
  unsigned t1 = min(v1, k), c1 = max(v1, k);
  unsigned t2 = min(v2, c1), c2 = max(v2, c1);
  v1 = t1; v2 = t2; v3 = min(v3, c2);
}

__global__ __launch_bounds__(256) void conv_pad(
    const float* __restrict__ src, unsigned short* __restrict__ hi,
    unsigned short* __restrict__ mid, int R, int C, int Rp, int Cp) {
  int t = blockIdx.x * 256 + threadIdx.x;
  if (t >= Rp * Cp) return;
  int r = t / Cp, c = t - r * Cp;
  float v = (r < R && c < C) ? src[(long)r * C + c] : 0.f;
  unsigned short h = f2bf(v);
  hi[t] = h;
  mid[t] = f2bf(v - bf2f(h));
}

__global__ __launch_bounds__(256) void emb_norm(const float* __restrict__ emb,
                                                float* __restrict__ enorm) {
  const int gtid = blockIdx.x * 256 + threadIdx.x;
  const int j = gtid >> 6;
  const int lane = threadIdx.x & 63;
  float4 v = *(const float4*)(emb + (long)j * 256 + (lane << 2));
  float s = v.x * v.x + v.y * v.y + v.z * v.z + v.w * v.w;
#pragma unroll
  for (int off = 1; off < 64; off <<= 1) s += __shfl_xor(s, off, 64);
  if (lane == 0) enorm[j] = s;
}

#define BK 32

enum { EPI_NONE = 0, EPI_RELU = 1, EPI_SIGMOID = 2 };
// OMODE: 0 = fp32 out, 1 = hi/mid split out, 2 = both
// Wave grid 2x2; wave tile (TMW*16) x (TNW*16); BM = TMW*32, BN = TNW*32.

template <int EPI, bool INDIRECT, bool ASPLIT, int OMODE, int TMW, int TNW>
__global__ __launch_bounds__(256, 4) void mfma_gemm(
    const float* __restrict__ Af, const unsigned short* __restrict__ Ahg,
    const unsigned short* __restrict__ Amg, const unsigned short* __restrict__ Bhi,
    const unsigned short* __restrict__ Bmid, const float* __restrict__ bias,
    float* __restrict__ Cf, unsigned short* __restrict__ Ohi,
    unsigned short* __restrict__ Omid, const int* __restrict__ aidx,
    int M, int N, int K, int Nreal) {
  constexpr int BM = TMW * 32;
  constexpr int BN = TNW * 32;
  constexpr int ASW = BM / 64;  // A 16-row slots per wave per array
  constexpr int BSW = BN / 64;  // B 16-row slots per wave per array
  constexpr int ACELL = BM / 32;  // fp32-A staging cells (BM=128 -> 4)
  __shared__ __align__(16) unsigned short Ah[BM][BK], Am[BM][BK];
  __shared__ __align__(16) unsigned short Bh[BN][BK], Bm[BN][BK];

  const int tid = threadIdx.x, lane = tid & 63, wave = tid >> 6;
  const int wm = wave >> 1, wn = wave & 1;
  const int row0 = blockIdx.y * BM, col0 = blockIdx.x * BN;
  const int kshort = (lane & 3) * 8;

  const unsigned short *aH[ASW ? ASW : 1], *aM2[ASW ? ASW : 1];
  const unsigned short *bH[BSW], *bM2[BSW];
  const float* aF[ACELL];
  if (ASPLIT) {
#pragma unroll
    for (int j = 0; j < ASW; j++) {
      const int rl = (wave * ASW + j) * 16 + (lane >> 2);
      const long ar = INDIRECT ? (long)aidx[row0 + rl] : (long)(row0 + rl);
      aH[j] = Ahg + ar * K + kshort;
      aM2[j] = Amg + ar * K + kshort;
    }
  } else {
#pragma unroll
    for (int i = 0; i < ACELL; i++)
      aF[i] = Af + (long)(row0 + i * 32 + (tid >> 3)) * K + (tid & 7) * 4;
  }
#pragma unroll
  for (int j = 0; j < BSW; j++) {
    const int rl = (wave * BSW + j) * 16 + (lane >> 2);
    bH[j] = Bhi + (long)(col0 + rl) * K + kshort;
    bM2[j] = Bmid + (long)(col0 + rl) * K + kshort;
  }

  floatx4 acc[TMW][TNW];
#pragma unroll
  for (int i = 0; i < TMW; i++)
#pragma unroll
    for (int j = 0; j < TNW; j++) acc[i][j] = (floatx4)0.f;

  for (int k0 = 0; k0 < K; k0 += BK) {
    float4 areg[ACELL];
    if (!ASPLIT) {
#pragma unroll
      for (int i = 0; i < ACELL; i++) areg[i] = *(const float4*)(aF[i] + k0);
    }
    __syncthreads();  // prev-iter LDS reads complete
#pragma unroll
    for (int j = 0; j < BSW; j++) {
      const int slot = wave * BSW + j;
      glds16(bH[j] + k0, &Bh[0][0] + slot * 512);
      glds16(bM2[j] + k0, &Bm[0][0] + slot * 512);
    }
    if (ASPLIT) {
#pragma unroll
      for (int j = 0; j < ASW; j++) {
        const int slot = wave * ASW + j;
        glds16(aH[j] + k0, &Ah[0][0] + slot * 512);
        glds16(aM2[j] + k0, &Am[0][0] + slot * 512);
      }
    } else {
#pragma unroll
      for (int i = 0; i < ACELL; i++) {
        const int r = i * 32 + (tid >> 3), q4 = (tid & 7) * 4;
        ushort4v h, m;
        h.x = f2bf(areg[i].x); m.x = f2bf(areg[i].x - bf2f(h.x));
        h.y = f2bf(areg[i].y); m.y = f2bf(areg[i].y - bf2f(h.y));
        h.z = f2bf(areg[i].z); m.z = f2bf(areg[i].z - bf2f(h.z));
        h.w = f2bf(areg[i].w); m.w = f2bf(areg[i].w - bf2f(h.w));
        *(ushort4v*)&Ah[r][q4] = h;
        *(ushort4v*)&Am[r][q4] = m;
      }
    }
    __syncthreads();  // staging published

    short8 ah[TMW], am[TMW];
#pragma unroll
    for (int tm = 0; tm < TMW; tm++) {
      const int rr = wm * (TMW * 16) + tm * 16 + (lane & 15);
      const int kk = (lane >> 4) * 8;
      ah[tm] = *(const short8*)&Ah[rr][kk];
      am[tm] = *(const short8*)&Am[rr][kk];
    }
#pragma unroll
    for (int tn = 0; tn < TNW; tn++) {
      const int rr = wn * (TNW * 16) + tn * 16 + (lane & 15);
      const int kk = (lane >> 4) * 8;
      short8 bh = *(const short8*)&Bh[rr][kk];
      short8 bm = *(const short8*)&Bm[rr][kk];
#pragma unroll
      for (int tm = 0; tm < TMW; tm++) {
        acc[tm][tn] = __builtin_amdgcn_mfma_f32_16x16x32_bf16(ah[tm], bh, acc[tm][tn], 0, 0, 0);
        acc[tm][tn] = __builtin_amdgcn_mfma_f32_16x16x32_bf16(ah[tm], bm, acc[tm][tn], 0, 0, 0);
        acc[tm][tn] = __builtin_amdgcn_mfma_f32_16x16x32_bf16(am[tm], bh, acc[tm][tn], 0, 0, 0);
      }
    }
  }

  // C/D layout: col = lane&15, row = (lane>>4)*4 + reg
  const int qd = lane >> 4, ln = lane & 15;
#pragma unroll
  for (int tn = 0; tn < TNW; tn++) {
    const int c = col0 + wn * (TNW * 16) + tn * 16 + ln;
    const float bb = (c < Nreal) ? bias[c] : 0.f;
#pragma unroll
    for (int tm = 0; tm < TMW; tm++) {
#pragma unroll
      for (int reg = 0; reg < 4; reg++) {
        const int r = row0 + wm * (TMW * 16) + tm * 16 + qd * 4 + reg;
        float v = acc[tm][tn][reg] + bb;
        if (EPI == EPI_RELU) v = fmaxf(v, 0.f);
        if (EPI == EPI_SIGMOID) v = 1.f / (1.f + __expf(-v));
        if (OMODE == 0 || OMODE == 2) Cf[(long)r * N + c] = v;
        if (OMODE == 1 || OMODE == 2) {
          unsigned short h = f2bf(v);
          Ohi[(long)r * N + c] = h;
          Omid[(long)r * N + c] = f2bf(v - bf2f(h));
        }
      }
    }
  }
}

// dist candidates: grid (8, M/128); block sweeps 256 cols in 2 chunks of 128.
// Branchless per-lane packed-key top-3, one cross-lane merge per block.
__global__ __launch_bounds__(256, 3) void dist_topk(
    const unsigned short* __restrict__ Zh, const unsigned short* __restrict__ Zm,
    const unsigned short* __restrict__ Eh, const unsigned short* __restrict__ Em,
    const float* __restrict__ enorm, int* __restrict__ pidx, int M) {
  const int K = 256;
  __shared__ __align__(16) unsigned short Ah[128][BK], Am[128][BK];
  __shared__ __align__(16) unsigned short Bh[128][BK], Bm[128][BK];
  __shared__ unsigned r1s[2][128], r2s[2][128], r3s[2][128];

  const int tid = threadIdx.x, lane = tid & 63, wave = tid >> 6;
  const int wm = wave >> 1, wn = wave & 1;
  const int row0 = blockIdx.y * 128;
  const int col_base = blockIdx.x * 256;
  const int kshort = (lane & 3) * 8;

  const unsigned short *aH[2], *aM2[2];
  int rlj[2];
#pragma unroll
  for (int j = 0; j < 2; j++) {
    rlj[j] = (wave * 2 + j) * 16 + (lane >> 2);
    aH[j] = Zh + (long)(row0 + rlj[j]) * K + kshort;
    aM2[j] = Zm + (long)(row0 + rlj[j]) * K + kshort;
  }

  unsigned k1[16], k2[16], k3[16];
#pragma unroll
  for (int s = 0; s < 16; s++) { k1[s] = 0xFFFFFFFFu; k2[s] = 0xFFFFFFFFu; k3[s] = 0xFFFFFFFFu; }

  for (int ch = 0; ch < 2; ch++) {
    const int col0 = col_base + ch * 128;
    floatx4 acc[4][4];
#pragma unroll
    for (int i = 0; i < 4; i++)
#pragma unroll
      for (int j = 0; j < 4; j++) acc[i][j] = (floatx4)0.f;

    for (int k0 = 0; k0 < K; k0 += BK) {
      __syncthreads();
#pragma unroll
      for (int j = 0; j < 2; j++) {
        const int slot = wave * 2 + j;
        glds16(aH[j] + k0, &Ah[0][0] + slot * 512);
        glds16(aM2[j] + k0, &Am[0][0] + slot * 512);
        glds16(Eh + (long)(col0 + rlj[j]) * K + kshort + k0, &Bh[0][0] + slot * 512);
        glds16(Em + (long)(col0 + rlj[j]) * K + kshort + k0, &Bm[0][0] + slot * 512);
      }
      __syncthreads();

      short8 ah[4], am[4];
#pragma unroll
      for (int tm = 0; tm < 4; tm++) {
        const int rr = wm * 64 + tm * 16 + (lane & 15);
        const int kk = (lane >> 4) * 8;
        ah[tm] = *(const short8*)&Ah[rr][kk];
        am[tm] = *(const short8*)&Am[rr][kk];
      }
#pragma unroll
      for (int tn = 0; tn < 4; tn++) {
        const int rr = wn * 64 + tn * 16 + (lane & 15);
        const int kk = (lane >> 4) * 8;
        short8 bh = *(const short8*)&Bh[rr][kk];
        short8 bm = *(const short8*)&Bm[rr][kk];
#pragma unroll
        for (int tm = 0; tm < 4; tm++) {
          acc[tm][tn] = __builtin_amdgcn_mfma_f32_16x16x32_bf16(ah[tm], bh, acc[tm][tn], 0, 0, 0);
          acc[tm][tn] = __builtin_amdgcn_mfma_f32_16x16x32_bf16(ah[tm], bm, acc[tm][tn], 0, 0, 0);
          acc[tm][tn] = __builtin_amdgcn_mfma_f32_16x16x32_bf16(am[tm], bh, acc[tm][tn], 0, 0, 0);
        }
      }
    }

#pragma unroll
    for (int tn = 0; tn < 4; tn++) {
      const int c = col0 + wn * 64 + tn * 16 + (lane & 15);
      const float en = enorm[c];
#pragma unroll
      for (int tm = 0; tm < 4; tm++)
#pragma unroll
        for (int reg = 0; reg < 4; reg++) {
          float d = en - 2.f * acc[tm][tn][reg];
          ins3(packkey(d, c), k1[tm * 4 + reg], k2[tm * 4 + reg], k3[tm * 4 + reg]);
        }
    }
  }

#pragma unroll
  for (int s = 0; s < 16; s++) {
#pragma unroll
    for (int off = 1; off < 16; off <<= 1) {
      unsigned o1 = __shfl_xor(k1[s], off, 64);
      unsigned o2 = __shfl_xor(k2[s], off, 64);
      unsigned o3 = __shfl_xor(k3[s], off, 64);
      ins3(o1, k1[s], k2[s], k3[s]);
      ins3(o2, k1[s], k2[s], k3[s]);
      ins3(o3, k1[s], k2[s], k3[s]);
    }
  }
  if ((lane & 15) == 0) {
#pragma unroll
    for (int s = 0; s < 16; s++) {
      int rl = wm * 64 + (s >> 2) * 16 + (lane >> 4) * 4 + (s & 3);
      r1s[wn][rl] = k1[s]; r2s[wn][rl] = k2[s]; r3s[wn][rl] = k3[s];
    }
  }
  __syncthreads();
  if (tid < 128) {
    unsigned v1 = r1s[0][tid], v2 = r2s[0][tid], v3 = r3s[0][tid];
    ins3(r1s[1][tid], v1, v2, v3);
    ins3(r2s[1][tid], v1, v2, v3);
    ins3(r3s[1][tid], v1, v2, v3);
    const long base = ((long)blockIdx.x * M + (row0 + tid)) * 4;
    pidx[base + 0] = (int)(v1 & 0x7FFu);
    pidx[base + 1] = (int)(v2 & 0x7FFu);
    pidx[base + 2] = (int)(v3 & 0x7FFu);
  }
}

// exact fp32 rescore of 24 candidates/row; one wave per row
__global__ __launch_bounds__(256) void rescore(
    const float* __restrict__ z, const float* __restrict__ emb,
    const float* __restrict__ enorm, const int* __restrict__ pidx,
    int* __restrict__ idx, int M) {
  const int wave = threadIdx.x >> 6, lane = threadIdx.x & 63;
  const int r = blockIdx.x * 4 + wave;
  float4 zv = *(const float4*)(z + (long)r * 256 + lane * 4);
  float best = FLT_MAX;
  int bi = 0x7fffffff;
  for (int g = 0; g < 8; g++) {
#pragma unroll
    for (int s = 0; s < 3; s++) {
      const int j = pidx[((long)g * M + r) * 4 + s];
      float4 ev = *(const float4*)(emb + (long)j * 256 + lane * 4);
      float t = zv.x * ev.x + zv.y * ev.y + zv.z * ev.z + zv.w * ev.w;
#pragma unroll
      for (int off = 1; off < 64; off <<= 1) t += __shfl_xor(t, off, 64);
      const float d = enorm[j] - 2.f * t;
      if (d < best || (d == best && j < bi)) { best = d; bi = j; }
    }
  }
  if (lane == 0) idx[r] = bi;
}

extern "C" void kernel_launch(void* const* d_in, const int* in_sizes, int n_in,
                              void* d_out, int out_size, void* d_ws, size_t ws_size,
                              hipStream_t stream) {
  const float* x   = (const float*)d_in[0];
  const float* W1  = (const float*)d_in[1];
  const float* b1  = (const float*)d_in[2];
  const float* W2  = (const float*)d_in[3];
  const float* b2  = (const float*)d_in[4];
  const float* W3  = (const float*)d_in[5];
  const float* b3  = (const float*)d_in[6];
  const float* W4  = (const float*)d_in[7];
  const float* b4  = (const float*)d_in[8];
  const float* emb = (const float*)d_in[9];
  float* out = (float*)d_out;

  const int BZ = 16384, IN = 1024, H = 400, Hp = 512, D = 256, NE = 2048;

  char* ws = (char*)d_ws;
  size_t off = 0;
  auto alloc = [&](size_t bytes) {
    void* p = ws + off;
    off += (bytes + 255) & ~(size_t)255;
    return p;
  };
  unsigned short* w1h = (unsigned short*)alloc((size_t)Hp * IN * 2);
  unsigned short* w1m = (unsigned short*)alloc((size_t)Hp * IN * 2);
  unsigned short* w2h = (unsigned short*)alloc((size_t)D * Hp * 2);
  unsigned short* w2m = (unsigned short*)alloc((size_t)D * Hp * 2);
  unsigned short* w3h = (unsigned short*)alloc((size_t)Hp * D * 2);
  unsigned short* w3m = (unsigned short*)alloc((size_t)Hp * D * 2);
  unsigned short* w4h = (unsigned short*)alloc((size_t)IN * Hp * 2);
  unsigned short* w4m = (unsigned short*)alloc((size_t)IN * Hp * 2);
  unsigned short* eh  = (unsigned short*)alloc((size_t)NE * D * 2);
  unsigned short* em  = (unsigned short*)alloc((size_t)NE * D * 2);
  float* enorm = (float*)alloc((size_t)NE * 4);
  unsigned short* h1h = (unsigned short*)alloc((size_t)BZ * Hp * 2);  // 16MB
  unsigned short* h1m = (unsigned short*)alloc((size_t)BZ * Hp * 2);  // 16MB
  float* zf = (float*)alloc((size_t)BZ * D * 4);                       // 16MB
  unsigned short* zh = (unsigned short*)alloc((size_t)BZ * D * 2);     // 8MB
  unsigned short* zm = (unsigned short*)alloc((size_t)BZ * D * 2);     // 8MB
  // aliases (lifetimes disjoint on the sequential stream):
  unsigned short* h3h = (unsigned short*)zf;   // zf dead after rescore
  unsigned short* h3m = zh;                    // zh+zm dead after dist
  int* pidx = (int*)h1h;                       // h1 dead after GEMM2
  int* idx  = ((int*)h1h) + (size_t)8 * BZ * 4;

  conv_pad<<<dim3((Hp * IN + 255) / 256), dim3(256), 0, stream>>>(W1, w1h, w1m, H, IN, Hp, IN);
  conv_pad<<<dim3((D * Hp + 255) / 256), dim3(256), 0, stream>>>(W2, w2h, w2m, D, H, D, Hp);
  conv_pad<<<dim3((Hp * D + 255) / 256), dim3(256), 0, stream>>>(W3, w3h, w3m, H, D, Hp, D);
  conv_pad<<<dim3((IN * Hp + 255) / 256), dim3(256), 0, stream>>>(W4, w4h, w4m, IN, H, IN, Hp);
  conv_pad<<<dim3((NE * D + 255) / 256), dim3(256), 0, stream>>>(emb, eh, em, NE, D, NE, D);
  emb_norm<<<dim3(NE * 64 / 256), dim3(256), 0, stream>>>(emb, enorm);

  // h1 = relu(x @ W1^T + b1) -> hi/mid [BZ][512]   BM=128,BN=64: 1024 blocks
  mfma_gemm<EPI_RELU, false, false, 1, 4, 2><<<dim3(Hp / 64, BZ / 128), dim3(256), 0, stream>>>(
      x, nullptr, nullptr, w1h, w1m, b1, nullptr, h1h, h1m, nullptr, BZ, Hp, IN, H);
  // z_e = h1 @ W2^T + b2 -> fp32 + hi/mid [BZ][256]   BM=64,BN=64: 1024 blocks
  mfma_gemm<EPI_NONE, false, true, 2, 2, 2><<<dim3(D / 64, BZ / 64), dim3(256), 0, stream>>>(
      nullptr, h1h, h1m, w2h, w2m, b2, zf, zh, zm, nullptr, BZ, D, Hp, D);
  // dist candidates: top-3 per 256-col group (8 groups, 1024 blocks)
  dist_topk<<<dim3(8, BZ / 128), dim3(256), 0, stream>>>(zh, zm, eh, em, enorm, pidx, BZ);
  // exact fp32 rescore of 24 -> idx
  rescore<<<dim3(BZ / 4), dim3(256), 0, stream>>>(zf, emb, enorm, pidx, idx, BZ);
  // h3 = relu(emb[idx] @ W3^T + b3) -> hi/mid [BZ][512]   1024 blocks
  mfma_gemm<EPI_RELU, true, true, 1, 4, 2><<<dim3(Hp / 64, BZ / 128), dim3(256), 0, stream>>>(
      nullptr, eh, em, w3h, w3m, b3, nullptr, h3h, h3m, idx, BZ, Hp, D, H);
  // out = sigmoid(h3 @ W4^T + b4) -> fp32 [BZ][1024]   2048 blocks
  mfma_gemm<EPI_SIGMOID, false, true, 0, 4, 2><<<dim3(IN / 64, BZ / 128), dim3(256), 0, stream>>>(
      nullptr, h3h, h3m, w4h, w4m, b4, out, nullptr, nullptr, nullptr, BZ, IN, Hp, IN);
}

// Round 8
// 349.397 us; speedup vs baseline: 1.4980x; 1.4732x over previous
//
#include <hip/hip_runtime.h>
#include <math.h>
#include <float.h>

// VQVAE forward, MI355X. Round 8: R4 skeleton (best: 404us) + decoder bf16x2
// (post-argmin error only passes sigmoid), dist XCD-affinity grid + 4 groups,
// zf dropped (rescore reconstructs z = hi+mid). Encoder/argmin stays bf16x3.

typedef __attribute__((ext_vector_type(8))) short short8;      // MFMA A/B frag
typedef __attribute__((ext_vector_type(4))) float floatx4;     // MFMA C/D frag
typedef __attribute__((ext_vector_type(4))) unsigned short ushort4v;

__device__ __forceinline__ unsigned short f2bf(float f) {
  union { float f; unsigned u; } v; v.f = f;
  unsigned u = v.u;
  return (unsigned short)((u + 0x7FFFu + ((u >> 16) & 1u)) >> 16);
}
__device__ __forceinline__ float bf2f(unsigned short s) {
  union { unsigned u; float f; } v; v.u = ((unsigned)s) << 16;
  return v.f;
}

__device__ __forceinline__ void glds16(const void* g, void* l) {
  __builtin_amdgcn_global_load_lds(
      (const __attribute__((address_space(1))) unsigned int*)g,
      (__attribute__((address_space(3))) unsigned int*)l, 16, 0, 0);
}

__device__ __forceinline__ unsigned packkey(float d, int c) {
  unsigned b = __float_as_uint(d);
  b = (b & 0x80000000u) ? ~b : (b | 0x80000000u);
  return (b & 0xFFFFF800u) | (unsigned)c;
}
__device__ __forceinline__ void ins3(unsigned k, unsigned& v1, unsigned& v2,
                                     unsigned& v3) {
  unsigned t1 = min(v1, k), c1 = max(v1, k);
  unsigned t2 = min(v2, c1), c2 = max(v2, c1);
  v1 = t1; v2 = t2; v3 = min(v3, c2);
}

__global__ __launch_bounds__(256) void conv_pad(
    const float* __restrict__ src, unsigned short* __restrict__ hi,
    unsigned short* __restrict__ mid, int R, int C, int Rp, int Cp) {
  int t = blockIdx.x * 256 + threadIdx.x;
  if (t >= Rp * Cp) return;
  int r = t / Cp, c = t - r * Cp;
  float v = (r < R && c < C) ? src[(long)r * C + c] : 0.f;
  unsigned short h = f2bf(v);
  hi[t] = h;
  mid[t] = f2bf(v - bf2f(h));
}

__global__ __launch_bounds__(256) void emb_norm(const float* __restrict__ emb,
                                                float* __restrict__ enorm) {
  const int gtid = blockIdx.x * 256 + threadIdx.x;
  const int j = gtid >> 6;
  const int lane = threadIdx.x & 63;
  float4 v = *(const float4*)(emb + (long)j * 256 + (lane << 2));
  float s = v.x * v.x + v.y * v.y + v.z * v.z + v.w * v.w;
#pragma unroll
  for (int off = 1; off < 64; off <<= 1) s += __shfl_xor(s, off, 64);
  if (lane == 0) enorm[j] = s;
}

#define BK 32

enum { EPI_NONE = 0, EPI_RELU = 1, EPI_SIGMOID = 2 };
// OMODE: 0 = fp32 out, 1 = hi/mid split out, 3 = hi-only bf16 out
// NPROD: 3 = ah*bh + ah*bm + am*bh (fp32-grade); 2 = ah*bh + ah*bm (A hi-only)
// Wave grid 2x2; wave tile (TMW*16) x (TNW*16); BM = TMW*32, BN = TNW*32.

template <int EPI, bool INDIRECT, bool ASPLIT, int OMODE, int TMW, int TNW, int NPROD>
__global__ __launch_bounds__(256, 3) void mfma_gemm(
    const float* __restrict__ Af, const unsigned short* __restrict__ Ahg,
    const unsigned short* __restrict__ Amg, const unsigned short* __restrict__ Bhi,
    const unsigned short* __restrict__ Bmid, const float* __restrict__ bias,
    float* __restrict__ Cf, unsigned short* __restrict__ Ohi,
    unsigned short* __restrict__ Omid, const int* __restrict__ aidx,
    int M, int N, int K, int Nreal) {
  constexpr int BM = TMW * 32;
  constexpr int BN = TNW * 32;
  constexpr int ASW = BM / 64;    // A 16-row slots per wave per array
  constexpr int BSW = BN / 64;    // B 16-row slots per wave per array
  constexpr int ACELL = BM / 32;  // fp32-A staging cells
  __shared__ __align__(16) unsigned short Ah[BM][BK];
  __shared__ __align__(16) unsigned short Am[(NPROD == 3) ? BM : 1][BK];
  __shared__ __align__(16) unsigned short Bh[BN][BK], Bm[BN][BK];

  const int tid = threadIdx.x, lane = tid & 63, wave = tid >> 6;
  const int wm = wave >> 1, wn = wave & 1;
  const int row0 = blockIdx.y * BM, col0 = blockIdx.x * BN;
  const int kshort = (lane & 3) * 8;

  const unsigned short *aH[ASW], *aM2[ASW], *bH[BSW], *bM2[BSW];
  const float* aF[ACELL];
  if (ASPLIT) {
#pragma unroll
    for (int j = 0; j < ASW; j++) {
      const int rl = (wave * ASW + j) * 16 + (lane >> 2);
      const long ar = INDIRECT ? (long)aidx[row0 + rl] : (long)(row0 + rl);
      aH[j] = Ahg + ar * K + kshort;
      if (NPROD == 3) aM2[j] = Amg + ar * K + kshort;
    }
  } else {
#pragma unroll
    for (int i = 0; i < ACELL; i++)
      aF[i] = Af + (long)(row0 + i * 32 + (tid >> 3)) * K + (tid & 7) * 4;
  }
#pragma unroll
  for (int j = 0; j < BSW; j++) {
    const int rl = (wave * BSW + j) * 16 + (lane >> 2);
    bH[j] = Bhi + (long)(col0 + rl) * K + kshort;
    bM2[j] = Bmid + (long)(col0 + rl) * K + kshort;
  }

  floatx4 acc[TMW][TNW];
#pragma unroll
  for (int i = 0; i < TMW; i++)
#pragma unroll
    for (int j = 0; j < TNW; j++) acc[i][j] = (floatx4)0.f;

  for (int k0 = 0; k0 < K; k0 += BK) {
    float4 areg[ACELL];
    if (!ASPLIT) {
#pragma unroll
      for (int i = 0; i < ACELL; i++) areg[i] = *(const float4*)(aF[i] + k0);
    }
    __syncthreads();  // prev-iter LDS reads complete
#pragma unroll
    for (int j = 0; j < BSW; j++) {
      const int slot = wave * BSW + j;
      glds16(bH[j] + k0, &Bh[0][0] + slot * 512);
      glds16(bM2[j] + k0, &Bm[0][0] + slot * 512);
    }
    if (ASPLIT) {
#pragma unroll
      for (int j = 0; j < ASW; j++) {
        const int slot = wave * ASW + j;
        glds16(aH[j] + k0, &Ah[0][0] + slot * 512);
        if (NPROD == 3) glds16(aM2[j] + k0, &Am[0][0] + slot * 512);
      }
    } else {
#pragma unroll
      for (int i = 0; i < ACELL; i++) {
        const int r = i * 32 + (tid >> 3), q4 = (tid & 7) * 4;
        ushort4v h, m;
        h.x = f2bf(areg[i].x); m.x = f2bf(areg[i].x - bf2f(h.x));
        h.y = f2bf(areg[i].y); m.y = f2bf(areg[i].y - bf2f(h.y));
        h.z = f2bf(areg[i].z); m.z = f2bf(areg[i].z - bf2f(h.z));
        h.w = f2bf(areg[i].w); m.w = f2bf(areg[i].w - bf2f(h.w));
        *(ushort4v*)&Ah[r][q4] = h;
        *(ushort4v*)&Am[r][q4] = m;
      }
    }
    __syncthreads();  // staging published

    short8 ah[TMW], am[TMW];
#pragma unroll
    for (int tm = 0; tm < TMW; tm++) {
      const int rr = wm * (TMW * 16) + tm * 16 + (lane & 15);
      const int kk = (lane >> 4) * 8;
      ah[tm] = *(const short8*)&Ah[rr][kk];
      if (NPROD == 3) am[tm] = *(const short8*)&Am[rr][kk];
    }
#pragma unroll
    for (int tn = 0; tn < TNW; tn++) {
      const int rr = wn * (TNW * 16) + tn * 16 + (lane & 15);
      const int kk = (lane >> 4) * 8;
      short8 bh = *(const short8*)&Bh[rr][kk];
      short8 bm = *(const short8*)&Bm[rr][kk];
#pragma unroll
      for (int tm = 0; tm < TMW; tm++) {
        acc[tm][tn] = __builtin_amdgcn_mfma_f32_16x16x32_bf16(ah[tm], bh, acc[tm][tn], 0, 0, 0);
        acc[tm][tn] = __builtin_amdgcn_mfma_f32_16x16x32_bf16(ah[tm], bm, acc[tm][tn], 0, 0, 0);
        if (NPROD == 3)
          acc[tm][tn] = __builtin_amdgcn_mfma_f32_16x16x32_bf16(am[tm], bh, acc[tm][tn], 0, 0, 0);
      }
    }
  }

  // C/D layout: col = lane&15, row = (lane>>4)*4 + reg
  const int qd = lane >> 4, ln = lane & 15;
#pragma unroll
  for (int tn = 0; tn < TNW; tn++) {
    const int c = col0 + wn * (TNW * 16) + tn * 16 + ln;
    const float bb = (c < Nreal) ? bias[c] : 0.f;
#pragma unroll
    for (int tm = 0; tm < TMW; tm++) {
#pragma unroll
      for (int reg = 0; reg < 4; reg++) {
        const int r = row0 + wm * (TMW * 16) + tm * 16 + qd * 4 + reg;
        float v = acc[tm][tn][reg] + bb;
        if (EPI == EPI_RELU) v = fmaxf(v, 0.f);
        if (EPI == EPI_SIGMOID) v = 1.f / (1.f + __expf(-v));
        if (OMODE == 0) {
          Cf[(long)r * N + c] = v;
        } else if (OMODE == 1) {
          unsigned short h = f2bf(v);
          Ohi[(long)r * N + c] = h;
          Omid[(long)r * N + c] = f2bf(v - bf2f(h));
        } else {  // OMODE == 3: hi only
          Ohi[(long)r * N + c] = f2bf(v);
        }
      }
    }
  }
}

// dist candidates: grid (M/128 rows, 4 groups); block sweeps 512 cols in 4
// chunks of 128. Grid-x = row-block => XCD = rowblock%8: codebook strips stay
// L2-resident per XCD. Branchless packed-key top-3, one cross-lane merge.
__global__ __launch_bounds__(256, 2) void dist_topk(
    const unsigned short* __restrict__ Zh, const unsigned short* __restrict__ Zm,
    const unsigned short* __restrict__ Eh, const unsigned short* __restrict__ Em,
    const float* __restrict__ enorm, int* __restrict__ pidx, int M) {
  const int K = 256;
  __shared__ __align__(16) unsigned short Ah[128][BK], Am[128][BK];
  __shared__ __align__(16) unsigned short Bh[128][BK], Bm[128][BK];
  __shared__ unsigned r1s[2][128], r2s[2][128], r3s[2][128];

  const int tid = threadIdx.x, lane = tid & 63, wave = tid >> 6;
  const int wm = wave >> 1, wn = wave & 1;
  const int row0 = blockIdx.x * 128;
  const int col_base = blockIdx.y * 512;
  const int kshort = (lane & 3) * 8;

  const unsigned short *aH[2], *aM2[2];
  int rlj[2];
#pragma unroll
  for (int j = 0; j < 2; j++) {
    rlj[j] = (wave * 2 + j) * 16 + (lane >> 2);
    aH[j] = Zh + (long)(row0 + rlj[j]) * K + kshort;
    aM2[j] = Zm + (long)(row0 + rlj[j]) * K + kshort;
  }

  unsigned k1[16], k2[16], k3[16];
#pragma unroll
  for (int s = 0; s < 16; s++) { k1[s] = 0xFFFFFFFFu; k2[s] = 0xFFFFFFFFu; k3[s] = 0xFFFFFFFFu; }

  for (int ch = 0; ch < 4; ch++) {
    const int col0 = col_base + ch * 128;
    floatx4 acc[4][4];
#pragma unroll
    for (int i = 0; i < 4; i++)
#pragma unroll
      for (int j = 0; j < 4; j++) acc[i][j] = (floatx4)0.f;

    for (int k0 = 0; k0 < K; k0 += BK) {
      __syncthreads();
#pragma unroll
      for (int j = 0; j < 2; j++) {
        const int slot = wave * 2 + j;
        glds16(aH[j] + k0, &Ah[0][0] + slot * 512);
        glds16(aM2[j] + k0, &Am[0][0] + slot * 512);
        glds16(Eh + (long)(col0 + rlj[j]) * K + kshort + k0, &Bh[0][0] + slot * 512);
        glds16(Em + (long)(col0 + rlj[j]) * K + kshort + k0, &Bm[0][0] + slot * 512);
      }
      __syncthreads();

      short8 ah[4], am[4];
#pragma unroll
      for (int tm = 0; tm < 4; tm++) {
        const int rr = wm * 64 + tm * 16 + (lane & 15);
        const int kk = (lane >> 4) * 8;
        ah[tm] = *(const short8*)&Ah[rr][kk];
        am[tm] = *(const short8*)&Am[rr][kk];
      }
#pragma unroll
      for (int tn = 0; tn < 4; tn++) {
        const int rr = wn * 64 + tn * 16 + (lane & 15);
        const int kk = (lane >> 4) * 8;
        short8 bh = *(const short8*)&Bh[rr][kk];
        short8 bm = *(const short8*)&Bm[rr][kk];
#pragma unroll
        for (int tm = 0; tm < 4; tm++) {
          acc[tm][tn] = __builtin_amdgcn_mfma_f32_16x16x32_bf16(ah[tm], bh, acc[tm][tn], 0, 0, 0);
          acc[tm][tn] = __builtin_amdgcn_mfma_f32_16x16x32_bf16(ah[tm], bm, acc[tm][tn], 0, 0, 0);
          acc[tm][tn] = __builtin_amdgcn_mfma_f32_16x16x32_bf16(am[tm], bh, acc[tm][tn], 0, 0, 0);
        }
      }
    }

#pragma unroll
    for (int tn = 0; tn < 4; tn++) {
      const int c = col0 + wn * 64 + tn * 16 + (lane & 15);
      const float en = enorm[c];
#pragma unroll
      for (int tm = 0; tm < 4; tm++)
#pragma unroll
        for (int reg = 0; reg < 4; reg++) {
          float d = en - 2.f * acc[tm][tn][reg];
          ins3(packkey(d, c), k1[tm * 4 + reg], k2[tm * 4 + reg], k3[tm * 4 + reg]);
        }
    }
  }

#pragma unroll
  for (int s = 0; s < 16; s++) {
#pragma unroll
    for (int off = 1; off < 16; off <<= 1) {
      unsigned o1 = __shfl_xor(k1[s], off, 64);
      unsigned o2 = __shfl_xor(k2[s], off, 64);
      unsigned o3 = __shfl_xor(k3[s], off, 64);
      ins3(o1, k1[s], k2[s], k3[s]);
      ins3(o2, k1[s], k2[s], k3[s]);
      ins3(o3, k1[s], k2[s], k3[s]);
    }
  }
  if ((lane & 15) == 0) {
#pragma unroll
    for (int s = 0; s < 16; s++) {
      int rl = wm * 64 + (s >> 2) * 16 + (lane >> 4) * 4 + (s & 3);
      r1s[wn][rl] = k1[s]; r2s[wn][rl] = k2[s]; r3s[wn][rl] = k3[s];
    }
  }
  __syncthreads();
  if (tid < 128) {
    unsigned v1 = r1s[0][tid], v2 = r2s[0][tid], v3 = r3s[0][tid];
    ins3(r1s[1][tid], v1, v2, v3);
    ins3(r2s[1][tid], v1, v2, v3);
    ins3(r3s[1][tid], v1, v2, v3);
    const long base = ((long)blockIdx.y * M + (row0 + tid)) * 4;
    pidx[base + 0] = (int)(v1 & 0x7FFu);
    pidx[base + 1] = (int)(v2 & 0x7FFu);
    pidx[base + 2] = (int)(v3 & 0x7FFu);
  }
}

// exact fp32 rescore of 12 candidates/row; z = hi + mid (bit-identical to the
// value the dist kernel scored). One wave per row.
__global__ __launch_bounds__(256) void rescore(
    const unsigned short* __restrict__ zh, const unsigned short* __restrict__ zm,
    const float* __restrict__ emb, const float* __restrict__ enorm,
    const int* __restrict__ pidx, int* __restrict__ idx, int M) {
  const int wave = threadIdx.x >> 6, lane = threadIdx.x & 63;
  const int r = blockIdx.x * 4 + wave;
  ushort4v hz = *(const ushort4v*)(zh + (long)r * 256 + lane * 4);
  ushort4v mz = *(const ushort4v*)(zm + (long)r * 256 + lane * 4);
  float4 zv;
  zv.x = bf2f(hz.x) + bf2f(mz.x);
  zv.y = bf2f(hz.y) + bf2f(mz.y);
  zv.z = bf2f(hz.z) + bf2f(mz.z);
  zv.w = bf2f(hz.w) + bf2f(mz.w);
  float best = FLT_MAX;
  int bi = 0x7fffffff;
  for (int g = 0; g < 4; g++) {
#pragma unroll
    for (int s = 0; s < 3; s++) {
      const int j = pidx[((long)g * M + r) * 4 + s];
      float4 ev = *(const float4*)(emb + (long)j * 256 + lane * 4);
      float t = zv.x * ev.x + zv.y * ev.y + zv.z * ev.z + zv.w * ev.w;
#pragma unroll
      for (int off = 1; off < 64; off <<= 1) t += __shfl_xor(t, off, 64);
      const float d = enorm[j] - 2.f * t;
      if (d < best || (d == best && j < bi)) { best = d; bi = j; }
    }
  }
  if (lane == 0) idx[r] = bi;
}

extern "C" void kernel_launch(void* const* d_in, const int* in_sizes, int n_in,
                              void* d_out, int out_size, void* d_ws, size_t ws_size,
                              hipStream_t stream) {
  const float* x   = (const float*)d_in[0];
  const float* W1  = (const float*)d_in[1];
  const float* b1  = (const float*)d_in[2];
  const float* W2  = (const float*)d_in[3];
  const float* b2  = (const float*)d_in[4];
  const float* W3  = (const float*)d_in[5];
  const float* b3  = (const float*)d_in[6];
  const float* W4  = (const float*)d_in[7];
  const float* b4  = (const float*)d_in[8];
  const float* emb = (const float*)d_in[9];
  float* out = (float*)d_out;

  const int BZ = 16384, IN = 1024, H = 400, Hp = 512, D = 256, NE = 2048;

  char* ws = (char*)d_ws;
  size_t off = 0;
  auto alloc = [&](size_t bytes) {
    void* p = ws + off;
    off += (bytes + 255) & ~(size_t)255;
    return p;
  };
  unsigned short* w1h = (unsigned short*)alloc((size_t)Hp * IN * 2);
  unsigned short* w1m = (unsigned short*)alloc((size_t)Hp * IN * 2);
  unsigned short* w2h = (unsigned short*)alloc((size_t)D * Hp * 2);
  unsigned short* w2m = (unsigned short*)alloc((size_t)D * Hp * 2);
  unsigned short* w3h = (unsigned short*)alloc((size_t)Hp * D * 2);
  unsigned short* w3m = (unsigned short*)alloc((size_t)Hp * D * 2);
  unsigned short* w4h = (unsigned short*)alloc((size_t)IN * Hp * 2);
  unsigned short* w4m = (unsigned short*)alloc((size_t)IN * Hp * 2);
  unsigned short* eh  = (unsigned short*)alloc((size_t)NE * D * 2);
  unsigned short* em  = (unsigned short*)alloc((size_t)NE * D * 2);
  float* enorm = (float*)alloc((size_t)NE * 4);
  unsigned short* h1h = (unsigned short*)alloc((size_t)BZ * Hp * 2);  // 16MB
  unsigned short* h1m = (unsigned short*)alloc((size_t)BZ * Hp * 2);  // 16MB
  unsigned short* zh  = (unsigned short*)alloc((size_t)BZ * D * 2);   // 8MB
  unsigned short* zm  = (unsigned short*)alloc((size_t)BZ * D * 2);   // 8MB
  // aliases (lifetimes disjoint on the sequential stream):
  int* pidx = (int*)h1h;                       // h1 dead after GEMM2 (1MB used)
  int* idx  = ((int*)h1h) + (size_t)4 * BZ * 4;
  unsigned short* h3h = h1m;                   // h1m dead after GEMM2 (16MB)

  conv_pad<<<dim3((Hp * IN + 255) / 256), dim3(256), 0, stream>>>(W1, w1h, w1m, H, IN, Hp, IN);
  conv_pad<<<dim3((D * Hp + 255) / 256), dim3(256), 0, stream>>>(W2, w2h, w2m, D, H, D, Hp);
  conv_pad<<<dim3((Hp * D + 255) / 256), dim3(256), 0, stream>>>(W3, w3h, w3m, H, D, Hp, D);
  conv_pad<<<dim3((IN * Hp + 255) / 256), dim3(256), 0, stream>>>(W4, w4h, w4m, IN, H, IN, Hp);
  conv_pad<<<dim3((NE * D + 255) / 256), dim3(256), 0, stream>>>(emb, eh, em, NE, D, NE, D);
  emb_norm<<<dim3(NE * 64 / 256), dim3(256), 0, stream>>>(emb, enorm);

  // h1 = relu(x @ W1^T + b1) -> hi/mid [BZ][512]   (bf16x3, 128x128, 512 blocks)
  mfma_gemm<EPI_RELU, false, false, 1, 4, 4, 3><<<dim3(Hp / 128, BZ / 128), dim3(256), 0, stream>>>(
      x, nullptr, nullptr, w1h, w1m, b1, nullptr, h1h, h1m, nullptr, BZ, Hp, IN, H);
  // z = h1 @ W2^T + b2 -> hi/mid [BZ][256]   (bf16x3, 64x128, 512 blocks)
  mfma_gemm<EPI_NONE, false, true, 1, 2, 4, 3><<<dim3(D / 128, BZ / 64), dim3(256), 0, stream>>>(
      nullptr, h1h, h1m, w2h, w2m, b2, nullptr, zh, zm, nullptr, BZ, D, Hp, D);
  // dist candidates: top-3 per 512-col group (XCD-affine grid), bf16x3
  dist_topk<<<dim3(BZ / 128, 4), dim3(256), 0, stream>>>(zh, zm, eh, em, enorm, pidx, BZ);
  // exact fp32 rescore of 12 -> idx
  rescore<<<dim3(BZ / 4), dim3(256), 0, stream>>>(zh, zm, emb, enorm, pidx, idx, BZ);
  // h3 = relu(emb[idx] @ W3^T + b3) -> bf16 hi only  (bf16x2 decoder, 512 blocks)
  mfma_gemm<EPI_RELU, true, true, 3, 4, 4, 2><<<dim3(Hp / 128, BZ / 128), dim3(256), 0, stream>>>(
      nullptr, eh, nullptr, w3h, w3m, b3, nullptr, h3h, nullptr, idx, BZ, Hp, D, H);
  // out = sigmoid(h3 @ W4^T + b4) -> fp32 [BZ][1024]  (bf16x2, 1024 blocks)
  mfma_gemm<EPI_SIGMOID, false, true, 0, 4, 4, 2><<<dim3(IN / 128, BZ / 128), dim3(256), 0, stream>>>(
      nullptr, h3h, nullptr, w4h, w4m, b4, out, nullptr, nullptr, nullptr, BZ, IN, Hp, IN);
}